// Round 4
// baseline (1409.087 us; speedup 1.0000x reference)
//
#include <hip/hip_runtime.h>
#include <math.h>

namespace {

constexpr int Bb = 4, Ss = 1024, Dd = 1024, Hh = 16, HDim = 64, Nn = 4096;
constexpr int Mm = Bb * Ss; // 4096

// ---------------------------------------------------------------------------
// fp32 GEMM v2: C[M,N] = A[M,K] @ W[N,K]^T (+ bias[N]).
// 128x128 tile, BK=16, 256 threads = 4 waves (2x2 quadrants of 64x64),
// lane = (lty<<3)|ltx so both LDS operand reads are 2-way (free) broadcasts.
// LDS double-buffered -> ONE barrier per K-tile; global loads prefetched a
// full tile ahead (latency hidden under 1024 FMAs of compute).
// MODE 0: C = acc + bias.  MODE 2: partial[blockIdx.y][n] = max over the
// tile's 128 rows (no bias) -- feeds the router's pooled max.
// ---------------------------------------------------------------------------
template <int MODE>
__global__ __launch_bounds__(256, 4) void gemm_f32(
    const float* __restrict__ A, const float* __restrict__ W,
    const float* __restrict__ bias, float* __restrict__ C, const int K,
    const int ldc) {
  __shared__ float As[2][16][128];  // [buf][k][m] 16 KB
  __shared__ float Ws[2][16][128];  // [buf][k][n] 16 KB
  const int tid = threadIdx.x;
  const int lane = tid & 63, wv = tid >> 6;
  const int wm = wv >> 1, wn = wv & 1;
  const int lty = lane >> 3, ltx = lane & 7;
  const int m0 = blockIdx.y * 128, n0 = blockIdx.x * 128;
  const int row0 = wm * 64 + lty * 8;  // within-tile output rows
  const int col0 = wn * 64 + ltx * 8;  // within-tile output cols
  const int srow = tid >> 1, shalf = tid & 1;  // staging: row, k-half
  const float* Ap = A + (size_t)(m0 + srow) * K + shalf * 8;
  const float* Wp = W + (size_t)(n0 + srow) * K + shalf * 8;

  // preload tile 0 into regs
  float4 ar0 = *(const float4*)(Ap);
  float4 ar1 = *(const float4*)(Ap + 4);
  float4 wr0 = *(const float4*)(Wp);
  float4 wr1 = *(const float4*)(Wp + 4);

  float acc[8][8] = {};
  const int NT = K / 16;
#pragma unroll 1
  for (int kt = 0; kt < NT; ++kt) {
    const int cb = kt & 1;
    // regs -> LDS (transposed to [k][m]); 2-way bank pattern = free
    As[cb][shalf * 8 + 0][srow] = ar0.x;
    As[cb][shalf * 8 + 1][srow] = ar0.y;
    As[cb][shalf * 8 + 2][srow] = ar0.z;
    As[cb][shalf * 8 + 3][srow] = ar0.w;
    As[cb][shalf * 8 + 4][srow] = ar1.x;
    As[cb][shalf * 8 + 5][srow] = ar1.y;
    As[cb][shalf * 8 + 6][srow] = ar1.z;
    As[cb][shalf * 8 + 7][srow] = ar1.w;
    Ws[cb][shalf * 8 + 0][srow] = wr0.x;
    Ws[cb][shalf * 8 + 1][srow] = wr0.y;
    Ws[cb][shalf * 8 + 2][srow] = wr0.z;
    Ws[cb][shalf * 8 + 3][srow] = wr0.w;
    Ws[cb][shalf * 8 + 4][srow] = wr1.x;
    Ws[cb][shalf * 8 + 5][srow] = wr1.y;
    Ws[cb][shalf * 8 + 6][srow] = wr1.z;
    Ws[cb][shalf * 8 + 7][srow] = wr1.w;
    // prefetch next tile (lands during the compute below)
    if (kt + 1 < NT) {
      const int kb = (kt + 1) * 16;
      ar0 = *(const float4*)(Ap + kb);
      ar1 = *(const float4*)(Ap + kb + 4);
      wr0 = *(const float4*)(Wp + kb);
      wr1 = *(const float4*)(Wp + kb + 4);
    }
    __syncthreads();  // staged data visible; prev buf reads already retired
#pragma unroll
    for (int kk = 0; kk < 16; ++kk) {
      float4 a0 = *(const float4*)&As[cb][kk][row0];
      float4 a1 = *(const float4*)&As[cb][kk][row0 + 4];
      float4 b0 = *(const float4*)&Ws[cb][kk][col0];
      float4 b1 = *(const float4*)&Ws[cb][kk][col0 + 4];
      float av[8] = {a0.x, a0.y, a0.z, a0.w, a1.x, a1.y, a1.z, a1.w};
      float bv[8] = {b0.x, b0.y, b0.z, b0.w, b1.x, b1.y, b1.z, b1.w};
#pragma unroll
      for (int i = 0; i < 8; ++i)
#pragma unroll
        for (int j = 0; j < 8; ++j)
          acc[i][j] = fmaf(av[i], bv[j], acc[i][j]);
    }
  }

  if constexpr (MODE == 0) {
    float4 bb0 = *(const float4*)&bias[n0 + col0];
    float4 bb1 = *(const float4*)&bias[n0 + col0 + 4];
    const float bv[8] = {bb0.x, bb0.y, bb0.z, bb0.w, bb1.x, bb1.y, bb1.z, bb1.w};
#pragma unroll
    for (int i = 0; i < 8; ++i) {
      float* crow = C + (size_t)(m0 + row0 + i) * ldc + n0 + col0;
      float4 o0 = {acc[i][0] + bv[0], acc[i][1] + bv[1], acc[i][2] + bv[2],
                   acc[i][3] + bv[3]};
      float4 o1 = {acc[i][4] + bv[4], acc[i][5] + bv[5], acc[i][6] + bv[6],
                   acc[i][7] + bv[7]};
      *(float4*)(crow) = o0;
      *(float4*)(crow + 4) = o1;
    }
  } else {
    // column max over this block's 128 rows -> partial[blockIdx.y][n]
    float cm[8];
#pragma unroll
    for (int j = 0; j < 8; ++j) {
      float m = acc[0][j];
#pragma unroll
      for (int i = 1; i < 8; ++i) m = fmaxf(m, acc[i][j]);
      m = fmaxf(m, __shfl_xor(m, 8));   // reduce over lty (lane bits 3..5)
      m = fmaxf(m, __shfl_xor(m, 16));
      m = fmaxf(m, __shfl_xor(m, 32));
      cm[j] = m;
    }
    __syncthreads();  // all LDS reads done; safe to reuse As
    float* buf = &As[0][0][0];  // 256 floats: [wm][col-in-tile]
    if (lty == 0) {
      float4 c0v = {cm[0], cm[1], cm[2], cm[3]};
      float4 c1v = {cm[4], cm[5], cm[6], cm[7]};
      *(float4*)&buf[wm * 128 + col0] = c0v;
      *(float4*)&buf[wm * 128 + col0 + 4] = c1v;
    }
    __syncthreads();
    if (tid < 128)
      C[(size_t)blockIdx.y * ldc + n0 + tid] = fmaxf(buf[tid], buf[128 + tid]);
  }
}

// ---------------------------------------------------------------------------
// Flash attention, fp32, v2. Grid: (S/64 q-tiles, B*H). Block 256.
// K/V tiles prefetched into regs one iteration ahead (no exposed HBM latency
// at the barrier); transpose stores XOR-swizzled to kill 4-way conflicts;
// __expf (v_exp_f32) for softmax.
// ---------------------------------------------------------------------------
__global__ __launch_bounds__(256) void attn_kernel(
    const float* __restrict__ qkv, float* __restrict__ ctx) {
  constexpr int LD = 68;
  __shared__ float Qs[64][LD];
  __shared__ float KPs[64][LD];  // K^T (swizzled) during scores; P (plain) during PV
  __shared__ float Vs[64][LD];   // [krow][d], col-swizzled by row bit2
  const int tid = threadIdx.x;
  const int tx = tid & 15, ty = tid >> 4;
  const int b = blockIdx.y >> 4, h = blockIdx.y & 15;
  const int q0 = blockIdx.x * 64;
  const size_t rowstride = 3 * Dd;
  const float* qbase = qkv + (size_t)b * Ss * rowstride + h * HDim;
  const float* kbase = qbase + Dd;
  const float* vbase = qbase + 2 * Dd;
  const int r = tid >> 2, c0 = (tid & 3) * 16;
  const int rx = (r & 4) ? 16 : 0;    // Q/V store swizzle key (row bit2)
  const int kx = (c0 & 32) ? 16 : 0;  // K^T store swizzle key (d bit5)
  {
    const float* qr = qbase + (size_t)(q0 + r) * rowstride + c0;
#pragma unroll
    for (int c = 0; c < 16; c += 4)
      *(float4*)&Qs[r][(c0 + c) ^ rx] = *(const float4*)(qr + c);
  }
  float4 kv[4], vv[4];
  {
    const float* kr = kbase + (size_t)r * rowstride + c0;
    const float* vr = vbase + (size_t)r * rowstride + c0;
#pragma unroll
    for (int c = 0; c < 4; ++c) {
      kv[c] = *(const float4*)(kr + 4 * c);
      vv[c] = *(const float4*)(vr + 4 * c);
    }
  }
  float O[4][4] = {};
  float mrow[4] = {-INFINITY, -INFINITY, -INFINITY, -INFINITY};
  float lrow[4] = {};
  const int qkey = (ty & 1) ? 16 : 0;  // read key for Q rows ty*4+i (bit2)
#pragma unroll 1
  for (int kt0 = 0; kt0 < Ss; kt0 += 64) {
    __syncthreads();  // prior PV reads of KPs/Vs done
#pragma unroll
    for (int c = 0; c < 4; ++c) {
      *(float4*)&Vs[r][(c0 + 4 * c) ^ rx] = vv[c];
      const int d = c0 + 4 * c;
      const int cc = r ^ kx;
      KPs[d + 0][cc] = kv[c].x;
      KPs[d + 1][cc] = kv[c].y;
      KPs[d + 2][cc] = kv[c].z;
      KPs[d + 3][cc] = kv[c].w;
    }
    __syncthreads();
    if (kt0 + 64 < Ss) {  // prefetch next K/V tile; lands during compute
      const float* kr = kbase + (size_t)(kt0 + 64 + r) * rowstride + c0;
      const float* vr = vbase + (size_t)(kt0 + 64 + r) * rowstride + c0;
#pragma unroll
      for (int c = 0; c < 4; ++c) {
        kv[c] = *(const float4*)(kr + 4 * c);
        vv[c] = *(const float4*)(vr + 4 * c);
      }
    }
    // scores: sc[i][j] = sum_d Q[ty*4+i][d] * K[tx*4+j][d]
    float sc[4][4] = {};
#pragma unroll
    for (int d0 = 0; d0 < HDim; d0 += 4) {
      const int kcol = (tx * 4) ^ ((d0 & 32) ? 16 : 0);
      float4 qa[4];
#pragma unroll
      for (int i = 0; i < 4; ++i)
        qa[i] = *(const float4*)&Qs[ty * 4 + i][d0 ^ qkey];
#pragma unroll
      for (int dd = 0; dd < 4; ++dd) {
        float4 kb = *(const float4*)&KPs[d0 + dd][kcol];
#pragma unroll
        for (int i = 0; i < 4; ++i) {
          float q = (dd == 0) ? qa[i].x : (dd == 1) ? qa[i].y
                    : (dd == 2) ? qa[i].z : qa[i].w;
          sc[i][0] = fmaf(q, kb.x, sc[i][0]);
          sc[i][1] = fmaf(q, kb.y, sc[i][1]);
          sc[i][2] = fmaf(q, kb.z, sc[i][2]);
          sc[i][3] = fmaf(q, kb.w, sc[i][3]);
        }
      }
    }
    __syncthreads();  // K^T reads done; safe to overwrite KPs with P
#pragma unroll
    for (int i = 0; i < 4; ++i) {
      float s0 = sc[i][0] * 0.125f, s1 = sc[i][1] * 0.125f;
      float s2 = sc[i][2] * 0.125f, s3 = sc[i][3] * 0.125f;
      float tm = fmaxf(fmaxf(s0, s1), fmaxf(s2, s3));
#pragma unroll
      for (int msk = 1; msk < 16; msk <<= 1) tm = fmaxf(tm, __shfl_xor(tm, msk));
      float mnew = fmaxf(mrow[i], tm);
      float p0 = __expf(s0 - mnew), p1 = __expf(s1 - mnew);
      float p2 = __expf(s2 - mnew), p3 = __expf(s3 - mnew);
      float4 pv4 = {p0, p1, p2, p3};
      *(float4*)&KPs[ty * 4 + i][tx * 4] = pv4;  // P, plain layout
      float rs = p0 + p1 + p2 + p3;
#pragma unroll
      for (int msk = 1; msk < 16; msk <<= 1) rs += __shfl_xor(rs, msk);
      float corr = __expf(mrow[i] - mnew);
      lrow[i] = lrow[i] * corr + rs;
      mrow[i] = mnew;
      O[i][0] *= corr; O[i][1] *= corr; O[i][2] *= corr; O[i][3] *= corr;
    }
    __syncthreads();  // P visible
    // PV: O[i][c] += sum_j P[ty*4+i][j] * V[j][tx*4+c]
#pragma unroll
    for (int j0 = 0; j0 < 64; j0 += 4) {
      const int vcol = (tx * 4) ^ ((j0 & 4) ? 16 : 0);
      float4 pa[4];
#pragma unroll
      for (int i = 0; i < 4; ++i) pa[i] = *(const float4*)&KPs[ty * 4 + i][j0];
#pragma unroll
      for (int jj = 0; jj < 4; ++jj) {
        float4 vb = *(const float4*)&Vs[j0 + jj][vcol];
#pragma unroll
        for (int i = 0; i < 4; ++i) {
          float p = (jj == 0) ? pa[i].x : (jj == 1) ? pa[i].y
                    : (jj == 2) ? pa[i].z : pa[i].w;
          O[i][0] = fmaf(p, vb.x, O[i][0]);
          O[i][1] = fmaf(p, vb.y, O[i][1]);
          O[i][2] = fmaf(p, vb.z, O[i][2]);
          O[i][3] = fmaf(p, vb.w, O[i][3]);
        }
      }
    }
  }
#pragma unroll
  for (int i = 0; i < 4; ++i) {
    float inv = 1.0f / lrow[i];
    const int srow = q0 + ty * 4 + i;
    float4 o = {O[i][0] * inv, O[i][1] * inv, O[i][2] * inv, O[i][3] * inv};
    *(float4*)(ctx + ((size_t)(b * Ss + srow)) * Dd + h * HDim + tx * 4) = o;
  }
}

// ---------------------------------------------------------------------------
// Router: bitonic full-sort of packed u64 keys (exact stable top-k).
// key = sortable(value)<<32 | (Nn-1-n): descending u64 order == descending
// value with ascending-index tiebreak == jax.lax.top_k order, exactly.
// ---------------------------------------------------------------------------
__device__ inline unsigned int f2s(float f) {
  unsigned int u = __float_as_uint(f);
  return (u >> 31) ? ~u : (u | 0x80000000u);
}
__device__ inline float s2f(unsigned int s) {
  unsigned int u = (s >> 31) ? (s & 0x7fffffffu) : ~s;
  return __uint_as_float(u);
}

__global__ __launch_bounds__(256) void router_kernel(
    const float* __restrict__ partial, const float* __restrict__ aff_b,
    const int* __restrict__ kp, float* __restrict__ out, int out_size) {
  __shared__ unsigned long long keys[Nn];  // 32 KB
  __shared__ float lorig[Nn];              // 16 KB
  __shared__ float rv[4];
  const int tid = threadIdx.x;
  const int b = blockIdx.x;
  const int kcount = *kp;
  float* idx_out = out;
  float* w_out = out + (out_size - Mm * Dd - Bb * Nn);
  for (int n = tid; n < Nn; n += 256) {
    float m = partial[(size_t)(b * 8) * Nn + n];
#pragma unroll
    for (int t = 1; t < 8; ++t)
      m = fmaxf(m, partial[(size_t)(b * 8 + t) * Nn + n]);
    float lg = (m + aff_b[n]) * 0.5f;  // /TEMPERATURE
    lorig[n] = lg;
    keys[n] = ((unsigned long long)f2s(lg) << 32) | (unsigned int)(Nn - 1 - n);
  }
  __syncthreads();
  for (int kk = 2; kk <= Nn; kk <<= 1) {
    for (int j = kk >> 1; j > 0; j >>= 1) {
#pragma unroll 4
      for (int t = tid; t < Nn / 2; t += 256) {
        const int i = 2 * j * (t / j) + (t % j);
        const int p = i + j;
        const bool desc = ((i & kk) == 0);
        unsigned long long a = keys[i], c = keys[p];
        if (desc ? (a < c) : (a > c)) { keys[i] = c; keys[p] = a; }
      }
      __syncthreads();
    }
  }
  const float gm = s2f((unsigned int)(keys[0] >> 32));
  float se = 0.f;
  for (int n = tid; n < Nn; n += 256) se += expf(lorig[n] - gm);
#pragma unroll
  for (int msk = 1; msk < 64; msk <<= 1) se += __shfl_xor(se, msk);
  if ((tid & 63) == 0) rv[tid >> 6] = se;
  __syncthreads();
  se = rv[0] + rv[1] + rv[2] + rv[3];
  __syncthreads();
  float es = 0.f;
  for (int p = tid; p < kcount; p += 256)
    es += expf(s2f((unsigned int)(keys[p] >> 32)) - gm);
#pragma unroll
  for (int msk = 1; msk < 64; msk <<= 1) es += __shfl_xor(es, msk);
  if ((tid & 63) == 0) rv[tid >> 6] = es;
  __syncthreads();
  es = rv[0] + rv[1] + rv[2] + rv[3];
  const float wd = es / se + 1e-8f;
  for (int n = tid; n < Nn; n += 256) w_out[(size_t)b * Nn + n] = 0.f;
  __syncthreads();
  for (int p = tid; p < kcount; p += 256) {
    const unsigned long long kkey = keys[p];
    const int n = Nn - 1 - (int)(kkey & 0xffffffffu);
    const float val = s2f((unsigned int)(kkey >> 32));
    idx_out[b * kcount + p] = (float)n;
    w_out[(size_t)b * Nn + n] = (expf(val - gm) / se) / wd;
  }
}

}  // namespace

extern "C" void kernel_launch(void* const* d_in, const int* in_sizes, int n_in,
                              void* d_out, int out_size, void* d_ws,
                              size_t ws_size, hipStream_t stream) {
  (void)in_sizes; (void)n_in; (void)ws_size;
  const float* x = (const float*)d_in[0];
  const float* in_proj_w = (const float*)d_in[1];
  const float* in_proj_b = (const float*)d_in[2];
  const float* out_w = (const float*)d_in[3];
  const float* out_b = (const float*)d_in[4];
  const float* aff_w = (const float*)d_in[5];
  const float* aff_b = (const float*)d_in[6];
  const int* kp = (const int*)d_in[7];

  float* qkv = (float*)d_ws;                 // [4096, 3072] = 50.3 MB
  float* ctxws = qkv + (size_t)Mm * 3 * Dd;  // [4096, 1024] = 16.8 MB
  float* partial = ctxws + (size_t)Mm * Dd;  // [32, 4096]   = 0.5 MB

  float* out = (float*)d_out;
  float* ctx_out = out + ((size_t)out_size - (size_t)Mm * Dd);  // context tail

  // 1) qkv = x @ in_proj_w^T + b
  gemm_f32<0><<<dim3(3 * Dd / 128, Mm / 128), 256, 0, stream>>>(
      x, in_proj_w, in_proj_b, qkv, Dd, 3 * Dd);
  // 2) attention -> ctxws (merged heads, fp32)
  attn_kernel<<<dim3(Ss / 64, Bb * Hh), 256, 0, stream>>>(qkv, ctxws);
  // 3) context = ctxws @ out_w^T + b  (into d_out tail)
  gemm_f32<0><<<dim3(Dd / 128, Mm / 128), 256, 0, stream>>>(
      ctxws, out_w, out_b, ctx_out, Dd, Dd);
  // 4) partial[mtile][n] = max over 128 rows of (context @ aff_w^T)
  gemm_f32<2><<<dim3(Nn / 128, Mm / 128), 256, 0, stream>>>(
      ctx_out, aff_w, nullptr, partial, Dd, Nn);
  // 5) router: pooled max, softmax, exact top-k, weights
  router_kernel<<<dim3(Bb), 256, 0, stream>>>(partial, aff_b, kp, out, out_size);
}